// Round 1
// baseline (243.327 us; speedup 1.0000x reference)
//
#include <hip/hip_runtime.h>

#define TPB 256
#define ROWS 32

// One block handles 32 contiguous node rows end-to-end:
//   stage1: h1 = relu(X@W1n+b1n)    (32x128)@(128x256)
//   stage2: h  = h1@W2n+b2n         (32x256)@(256x128)  -> global h_out + LDS
//   stage3: t1 = relu(h@(W1e_t+W1e_b)+b1e)  (32x128)@(128x128)
//   stage4: e  = (t1@w2e+b2e)/2048  -> LDS
//   stage5: edge[row, 0..2047] = e[row] broadcast write (float4, coalesced)
// LDS: xs 16KB (reused as t1) + h1 33.3KB (stride 260, conflict-free) +
//      hh 16.9KB (stride 132) = 66.7KB -> 2 blocks/CU.
__global__ __launch_bounds__(TPB, 2)
void fused_node_edge(const float* __restrict__ x,
                     const float* __restrict__ w1n, const float* __restrict__ b1n,
                     const float* __restrict__ w2n, const float* __restrict__ b2n,
                     const float* __restrict__ w1e, const float* __restrict__ b1e,
                     const float* __restrict__ w2e, const float* __restrict__ b2e,
                     float* __restrict__ h_out, float* __restrict__ edge_out)
{
    __shared__ float xs[ROWS * 128];    // x tile; reused as t1 after stage 1
    __shared__ float h1s[ROWS * 260];   // padded stride: banks (4r+j)%32 distinct
    __shared__ float hhs[ROWS * 132];   // padded stride
    __shared__ float es[ROWS];

    const int t = threadIdx.x;
    const int row0 = blockIdx.x * ROWS;

    // ---- load X tile: 32x128 contiguous floats = 1024 float4 ----
    {
        const float4* __restrict__ x4 = (const float4*)(x + (size_t)row0 * 128);
        float4* xs4 = (float4*)xs;
#pragma unroll
        for (int i = 0; i < 4; ++i) xs4[t + i * TPB] = x4[t + i * TPB];
    }
    __syncthreads();

    // ---- stage 1: h1 = relu(X @ W1n + b1n) ----
    {
        const int c0 = (t & 31) * 8;   // 32 col-groups of 8
        const int r0 = (t >> 5) * 4;   // 8 row-groups of 4
        const float4* __restrict__ w4 = (const float4*)w1n;
        const float4 bA = ((const float4*)b1n)[c0 >> 2];
        const float4 bB = ((const float4*)b1n)[(c0 >> 2) + 1];
        float acc[4][8];
#pragma unroll
        for (int i = 0; i < 4; ++i) {
            acc[i][0] = bA.x; acc[i][1] = bA.y; acc[i][2] = bA.z; acc[i][3] = bA.w;
            acc[i][4] = bB.x; acc[i][5] = bB.y; acc[i][6] = bB.z; acc[i][7] = bB.w;
        }
#pragma unroll 4
        for (int d = 0; d < 128; ++d) {
            const float4 wa = w4[d * 64 + (c0 >> 2)];
            const float4 wb = w4[d * 64 + (c0 >> 2) + 1];
            float xv[4];
#pragma unroll
            for (int i = 0; i < 4; ++i) xv[i] = xs[(r0 + i) * 128 + d];
            const float w[8] = {wa.x, wa.y, wa.z, wa.w, wb.x, wb.y, wb.z, wb.w};
#pragma unroll
            for (int i = 0; i < 4; ++i)
#pragma unroll
                for (int j = 0; j < 8; ++j)
                    acc[i][j] = fmaf(xv[i], w[j], acc[i][j]);
        }
#pragma unroll
        for (int i = 0; i < 4; ++i)
#pragma unroll
            for (int j = 0; j < 8; ++j)
                h1s[(r0 + i) * 260 + c0 + j] = fmaxf(acc[i][j], 0.0f);
    }
    __syncthreads();

    // ---- stage 2: h = h1 @ W2n + b2n ----
    {
        const int c0 = (t & 15) * 8;   // 16 col-groups of 8
        const int r0 = (t >> 4) * 2;   // 16 row-groups of 2
        const float4* __restrict__ w4 = (const float4*)w2n;
        const float4 bA = ((const float4*)b2n)[c0 >> 2];
        const float4 bB = ((const float4*)b2n)[(c0 >> 2) + 1];
        float acc[2][8];
#pragma unroll
        for (int i = 0; i < 2; ++i) {
            acc[i][0] = bA.x; acc[i][1] = bA.y; acc[i][2] = bA.z; acc[i][3] = bA.w;
            acc[i][4] = bB.x; acc[i][5] = bB.y; acc[i][6] = bB.z; acc[i][7] = bB.w;
        }
#pragma unroll 4
        for (int j = 0; j < 256; ++j) {
            const float4 wa = w4[j * 32 + (c0 >> 2)];
            const float4 wb = w4[j * 32 + (c0 >> 2) + 1];
            const float h0 = h1s[(r0 + 0) * 260 + j];
            const float h1v = h1s[(r0 + 1) * 260 + j];
            const float w[8] = {wa.x, wa.y, wa.z, wa.w, wb.x, wb.y, wb.z, wb.w};
#pragma unroll
            for (int k = 0; k < 8; ++k) {
                acc[0][k] = fmaf(h0, w[k], acc[0][k]);
                acc[1][k] = fmaf(h1v, w[k], acc[1][k]);
            }
        }
#pragma unroll
        for (int i = 0; i < 2; ++i) {
            const int gr = row0 + r0 + i;
            float4 lo = make_float4(acc[i][0], acc[i][1], acc[i][2], acc[i][3]);
            float4 hi = make_float4(acc[i][4], acc[i][5], acc[i][6], acc[i][7]);
            float4* hp = (float4*)(h_out + (size_t)gr * 128 + c0);
            hp[0] = lo;
            hp[1] = hi;
#pragma unroll
            for (int j = 0; j < 8; ++j)
                hhs[(r0 + i) * 132 + c0 + j] = acc[i][j];
        }
    }
    __syncthreads();

    // ---- stage 3: t1 = relu(h @ (W1e_top + W1e_bot) + b1e) ----
    float* t1s = xs;  // reuse (x tile dead after stage 1; barriers in between)
    {
        const int c0 = (t & 15) * 8;
        const int r0 = (t >> 4) * 2;
        const float4* __restrict__ w4 = (const float4*)w1e;
        const float4 bA = ((const float4*)b1e)[c0 >> 2];
        const float4 bB = ((const float4*)b1e)[(c0 >> 2) + 1];
        float acc[2][8];
#pragma unroll
        for (int i = 0; i < 2; ++i) {
            acc[i][0] = bA.x; acc[i][1] = bA.y; acc[i][2] = bA.z; acc[i][3] = bA.w;
            acc[i][4] = bB.x; acc[i][5] = bB.y; acc[i][6] = bB.z; acc[i][7] = bB.w;
        }
#pragma unroll 2
        for (int l = 0; l < 128; ++l) {
            const float4 wa1 = w4[l * 32 + (c0 >> 2)];
            const float4 wb1 = w4[l * 32 + (c0 >> 2) + 1];
            const float4 wa2 = w4[(l + 128) * 32 + (c0 >> 2)];
            const float4 wb2 = w4[(l + 128) * 32 + (c0 >> 2) + 1];
            const float h0 = hhs[(r0 + 0) * 132 + l];
            const float h1v = hhs[(r0 + 1) * 132 + l];
            const float w[8] = {wa1.x + wa2.x, wa1.y + wa2.y, wa1.z + wa2.z, wa1.w + wa2.w,
                                wb1.x + wb2.x, wb1.y + wb2.y, wb1.z + wb2.z, wb1.w + wb2.w};
#pragma unroll
            for (int k = 0; k < 8; ++k) {
                acc[0][k] = fmaf(h0, w[k], acc[0][k]);
                acc[1][k] = fmaf(h1v, w[k], acc[1][k]);
            }
        }
#pragma unroll
        for (int i = 0; i < 2; ++i)
#pragma unroll
            for (int j = 0; j < 8; ++j)
                t1s[(r0 + i) * 128 + c0 + j] = fmaxf(acc[i][j], 0.0f);
    }
    __syncthreads();

    // ---- stage 4: e[r] = (t1[r,:] . w2e + b2e) / 2048 ----
    {
        const int r = t >> 3;  // 32 rows
        const int s = t & 7;   // 8 lanes per row
        const float* tr = t1s + r * 128 + s * 16;
        const float* wv = w2e + s * 16;
        float sum = 0.0f;
#pragma unroll
        for (int k = 0; k < 16; ++k) sum = fmaf(tr[k], wv[k], sum);
        sum += __shfl_down(sum, 4, 8);
        sum += __shfl_down(sum, 2, 8);
        sum += __shfl_down(sum, 1, 8);
        if (s == 0) es[r] = (sum + b2e[0]) * (1.0f / 2048.0f);
    }
    __syncthreads();

    // ---- stage 5: edge broadcast write, 32 rows x 2048 floats ----
    {
        float4* __restrict__ e4 = (float4*)(edge_out + (size_t)row0 * 2048);
#pragma unroll 4
        for (int r = 0; r < ROWS; ++r) {
            const float ev = es[r];
            const float4 v = make_float4(ev, ev, ev, ev);
            e4[r * 512 + t] = v;
            e4[r * 512 + t + 256] = v;
        }
    }
}

extern "C" void kernel_launch(void* const* d_in, const int* in_sizes, int n_in,
                              void* d_out, int out_size, void* d_ws, size_t ws_size,
                              hipStream_t stream) {
    const float* x   = (const float*)d_in[0];
    const float* w1n = (const float*)d_in[1];
    const float* b1n = (const float*)d_in[2];
    const float* w2n = (const float*)d_in[3];
    const float* b2n = (const float*)d_in[4];
    const float* w1e = (const float*)d_in[5];
    const float* b1e = (const float*)d_in[6];
    const float* w2e = (const float*)d_in[7];
    const float* b2e = (const float*)d_in[8];

    float* h_out    = (float*)d_out;                              // (8,2048,128)
    float* edge_out = (float*)d_out + (size_t)8 * 2048 * 128;     // (8,2048,2048)

    // 16384 rows / 32 rows per block = 512 blocks
    fused_node_edge<<<dim3(512), dim3(TPB), 0, stream>>>(
        x, w1n, b1n, w2n, b2n, w1e, b1e, w2e, b2e, h_out, edge_out);
}